// Round 1
// baseline (393.173 us; speedup 1.0000x reference)
//
#include <hip/hip_runtime.h>
#include <cstddef>

#define F 128  // F_IN == UNITS == 128

// ---------------------------------------------------------------------------
// Kernel 1: H = X @ W   (fp32, vector ALU — no fp32 MFMA on CDNA4)
// Block = 256 threads, 32 rows of X per block.
// W (64 KB) + 32 X-rows (16 KB) staged in LDS -> 80 KB, 2 blocks/CU.
// Each thread computes a 4x4 output micro-tile (rows r0..r0+3, cols c0..c0+3).
// ---------------------------------------------------------------------------
__global__ __launch_bounds__(256) void gemm_xw(const float* __restrict__ X,
                                               const float* __restrict__ W,
                                               float* __restrict__ H,
                                               int n_nodes) {
  __shared__ float Ws[F * F];    // 64 KB
  __shared__ float Xs[32 * F];   // 16 KB
  const int tid = threadIdx.x;

  // Stage W (float4 coalesced)
  const float4* W4 = (const float4*)W;
  float4* Ws4 = (float4*)Ws;
  #pragma unroll
  for (int i = 0; i < (F * F / 4) / 256; ++i)
    Ws4[tid + i * 256] = W4[tid + i * 256];

  // Stage 32 rows of X (float4 coalesced), guarded for a partial last block
  const int row0 = blockIdx.x * 32;
  const float4* X4 = (const float4*)X;
  float4* Xs4 = (float4*)Xs;
  #pragma unroll
  for (int i = 0; i < (32 * F / 4) / 256; ++i) {
    int idx = tid + i * 256;                 // [0, 1024) float4s
    int r = row0 + idx / (F / 4);
    Xs4[idx] = (r < n_nodes) ? X4[(size_t)r * (F / 4) + (idx % (F / 4))]
                             : make_float4(0.f, 0.f, 0.f, 0.f);
  }
  __syncthreads();

  const int lane = tid & 31;   // 32 col-groups * 4 cols = 128 cols
  const int rg = tid >> 5;     // 8 row-groups  * 4 rows = 32 rows
  const int c0 = lane * 4;
  const int r0 = rg * 4;

  float acc[4][4];
  #pragma unroll
  for (int i = 0; i < 4; ++i)
    #pragma unroll
    for (int j = 0; j < 4; ++j) acc[i][j] = 0.f;

  #pragma unroll 4
  for (int k = 0; k < F; ++k) {
    const float4 w = *(const float4*)&Ws[k * F + c0];   // ds_read_b128
    #pragma unroll
    for (int i = 0; i < 4; ++i) {
      const float x = Xs[(r0 + i) * F + k];             // broadcast-ish
      acc[i][0] += x * w.x;
      acc[i][1] += x * w.y;
      acc[i][2] += x * w.z;
      acc[i][3] += x * w.w;
    }
  }

  #pragma unroll
  for (int i = 0; i < 4; ++i) {
    const int r = row0 + r0 + i;
    if (r < n_nodes) {
      float4 v = make_float4(acc[i][0], acc[i][1], acc[i][2], acc[i][3]);
      *(float4*)&H[(size_t)r * F + c0] = v;
    }
  }
}

// ---------------------------------------------------------------------------
// Kernel 2: out[n,:] = sigmoid( sum_{e in row n} val[e]*H[col[e],:] + bias )
// edge_row is SORTED -> one block per node, binary-search the edge range.
// No atomics, no init pass, output written exactly once.
// ---------------------------------------------------------------------------
__device__ __forceinline__ int lower_bound_i32(const int* __restrict__ a,
                                               int n, int key) {
  int lo = 0, hi = n;
  while (lo < hi) {
    int mid = (lo + hi) >> 1;
    if (a[mid] < key) lo = mid + 1; else hi = mid;
  }
  return lo;
}

__global__ __launch_bounds__(128) void spmm_bias_sigmoid(
    const int* __restrict__ erow, const int* __restrict__ ecol,
    const float* __restrict__ eval, const float* __restrict__ H,
    const float* __restrict__ bias, float* __restrict__ out, int n_edges) {
  const int node = blockIdx.x;
  const int f = threadIdx.x;  // 0..127, feature dim -> coalesced H gather

  // Uniform (threadIdx-independent) searches -> compiler can scalarize
  const int lo = lower_bound_i32(erow, n_edges, node);
  const int hi = lower_bound_i32(erow, n_edges, node + 1);

  float acc = 0.f;
  #pragma unroll 4
  for (int e = lo; e < hi; ++e) {
    const int c = ecol[e];        // uniform across block
    const float v = eval[e];      // uniform across block
    acc += v * H[(size_t)c * F + f];  // 512B coalesced gather per edge
  }
  acc += bias[f];
  out[(size_t)node * F + f] = 1.f / (1.f + expf(-acc));
}

// ---------------------------------------------------------------------------
extern "C" void kernel_launch(void* const* d_in, const int* in_sizes, int n_in,
                              void* d_out, int out_size, void* d_ws, size_t ws_size,
                              hipStream_t stream) {
  const float* X    = (const float*)d_in[0];
  const int*   erow = (const int*)  d_in[1];  // harness delivers ints as int32
  const int*   ecol = (const int*)  d_in[2];
  const float* eval = (const float*)d_in[3];
  const float* W    = (const float*)d_in[4];
  const float* bias = (const float*)d_in[5];
  float* out = (float*)d_out;
  float* H   = (float*)d_ws;                  // 100000*128*4 = 51.2 MB scratch

  const int n_nodes = in_sizes[0] / F;
  const int n_edges = in_sizes[1];

  gemm_xw<<<(n_nodes + 31) / 32, 256, 0, stream>>>(X, W, H, n_nodes);
  spmm_bias_sigmoid<<<n_nodes, 128, 0, stream>>>(erow, ecol, eval, H, bias,
                                                 out, n_edges);
}

// Round 2
// 297.963 us; speedup vs baseline: 1.3195x; 1.3195x over previous
//
#include <hip/hip_runtime.h>
#include <cstddef>

#define F 128  // F_IN == UNITS == 128

// ---------------------------------------------------------------------------
// Kernel 0: build row_ptr[N+1] from SORTED erow (edge-parallel, no search).
// row_ptr[k] = lower_bound(erow, k). Thread e fills rows (erow[e-1], erow[e]].
// ---------------------------------------------------------------------------
__global__ __launch_bounds__(256) void build_row_ptr(const int* __restrict__ erow,
                                                     int n_edges, int n_nodes,
                                                     int* __restrict__ row_ptr) {
  const int e = blockIdx.x * 256 + threadIdx.x;
  if (e > n_edges) return;
  int r_lo, r_hi, val;
  if (e == 0) {
    r_lo = 0; r_hi = erow[0]; val = 0;
  } else if (e == n_edges) {
    r_lo = erow[n_edges - 1] + 1; r_hi = n_nodes; val = n_edges;
  } else {
    const int rp = erow[e - 1], rc = erow[e];
    r_lo = rp + 1; r_hi = rc; val = e;
  }
  for (int r = r_lo; r <= r_hi; ++r) row_ptr[r] = val;
}

// ---------------------------------------------------------------------------
// Kernel 1: H = X @ W  (fp32 vector ALU). 512 threads = 64 rows/block.
// W (64 KB) in LDS; X read once from global as float4 (broadcast within
// lane-group). 4x4 register micro-tile per thread. 16 waves/CU (50% occ).
// ---------------------------------------------------------------------------
__global__ __launch_bounds__(512) void gemm_xw(const float* __restrict__ X,
                                               const float* __restrict__ W,
                                               float* __restrict__ H,
                                               int n_nodes) {
  __shared__ float Ws[F * F];  // 64 KB
  const int tid = threadIdx.x;

  const float4* W4 = (const float4*)W;
  float4* Ws4 = (float4*)Ws;
  #pragma unroll
  for (int i = 0; i < 8; ++i) Ws4[tid + i * 512] = W4[tid + i * 512];
  __syncthreads();

  const int c0 = (tid & 31) * 4;         // 32 col-groups x 4 cols
  const int rg = tid >> 5;               // 16 row-groups x 4 rows
  const int row0 = blockIdx.x * 64 + rg * 4;

  // Clamp row pointers (garbage rows computed but never stored)
  const float* Xr[4];
  #pragma unroll
  for (int i = 0; i < 4; ++i) {
    int r = row0 + i;
    if (r > n_nodes - 1) r = n_nodes - 1;
    Xr[i] = X + (size_t)r * F;
  }

  float acc[4][4];
  #pragma unroll
  for (int i = 0; i < 4; ++i)
    #pragma unroll
    for (int j = 0; j < 4; ++j) acc[i][j] = 0.f;

  #pragma unroll 2
  for (int kk = 0; kk < F; kk += 4) {
    float4 x[4];
    #pragma unroll
    for (int i = 0; i < 4; ++i) x[i] = *(const float4*)(Xr[i] + kk);
    #pragma unroll
    for (int t = 0; t < 4; ++t) {
      const float4 w = *(const float4*)&Ws[(kk + t) * F + c0];  // ds_read_b128
      #pragma unroll
      for (int i = 0; i < 4; ++i) {
        const float xs = (&x[i].x)[t];
        acc[i][0] += xs * w.x;
        acc[i][1] += xs * w.y;
        acc[i][2] += xs * w.z;
        acc[i][3] += xs * w.w;
      }
    }
  }

  #pragma unroll
  for (int i = 0; i < 4; ++i) {
    const int r = row0 + i;
    if (r < n_nodes)
      *(float4*)&H[(size_t)r * F + c0] =
          make_float4(acc[i][0], acc[i][1], acc[i][2], acc[i][3]);
  }
}

// ---------------------------------------------------------------------------
// Kernel 2: out[n,:] = sigmoid( sum_{e in row n} val[e]*H[col[e],:] + bias )
// 2 nodes per 128-thread block. Edge (col,val) fetched 64-at-a-time with one
// coalesced load per wave, broadcast via v_readlane (wave-uniform j).
// Dual accumulators + unroll-4 keep up to 8 independent gathers in flight.
// ---------------------------------------------------------------------------
__device__ __forceinline__ int bcast_i(int x, int l) {
  return __builtin_amdgcn_readlane(x, l);
}
__device__ __forceinline__ float bcast_f(float x, int l) {
  return __int_as_float(__builtin_amdgcn_readlane(__float_as_int(x), l));
}

__global__ __launch_bounds__(128) void spmm_bias_sigmoid(
    const int* __restrict__ row_ptr, const int* __restrict__ ecol,
    const float* __restrict__ eval, const float* __restrict__ H,
    const float* __restrict__ bias, float* __restrict__ out, int n_nodes) {
  const int n0 = blockIdx.x * 2;
  const int n1 = n0 + 1;
  const int f = threadIdx.x;     // feature index 0..127
  const int lane = f & 63;
  const bool has1 = (n1 < n_nodes);

  const int lo0 = row_ptr[n0];
  const int hi0 = row_ptr[n0 + 1];
  const int lo1 = has1 ? row_ptr[n1] : 0;
  const int hi1 = has1 ? row_ptr[n1 + 1] : 0;
  const int d0 = hi0 - lo0, d1 = hi1 - lo1;
  const int dmax = d0 > d1 ? d0 : d1;

  float acc0 = 0.f, acc1 = 0.f;
  for (int base = 0; base < dmax; base += 64) {
    int c0v = 0, c1v = 0;
    float v0v = 0.f, v1v = 0.f;
    if (base + lane < d0) {
      const int i0 = lo0 + base + lane;
      c0v = ecol[i0]; v0v = eval[i0];
    }
    if (base + lane < d1) {
      const int i1 = lo1 + base + lane;
      c1v = ecol[i1]; v1v = eval[i1];
    }
    int cnt = dmax - base;
    if (cnt > 64) cnt = 64;
    #pragma unroll 4
    for (int j = 0; j < cnt; ++j) {
      // padded lanes carry c=0, v=0 -> safe load of H[0,:], zero contribution
      const int cc0 = bcast_i(c0v, j);
      const float vv0 = bcast_f(v0v, j);
      const int cc1 = bcast_i(c1v, j);
      const float vv1 = bcast_f(v1v, j);
      acc0 += vv0 * H[(size_t)cc0 * F + f];
      acc1 += vv1 * H[(size_t)cc1 * F + f];
    }
  }
  const float b = bias[f];
  out[(size_t)n0 * F + f] = 1.f / (1.f + expf(-(acc0 + b)));
  if (has1) out[(size_t)n1 * F + f] = 1.f / (1.f + expf(-(acc1 + b)));
}

// ---------------------------------------------------------------------------
extern "C" void kernel_launch(void* const* d_in, const int* in_sizes, int n_in,
                              void* d_out, int out_size, void* d_ws, size_t ws_size,
                              hipStream_t stream) {
  const float* X    = (const float*)d_in[0];
  const int*   erow = (const int*)  d_in[1];
  const int*   ecol = (const int*)  d_in[2];
  const float* eval = (const float*)d_in[3];
  const float* W    = (const float*)d_in[4];
  const float* bias = (const float*)d_in[5];
  float* out = (float*)d_out;

  const int n_nodes = in_sizes[0] / F;
  const int n_edges = in_sizes[1];

  float* H = (float*)d_ws;  // 51.2 MB
  int* row_ptr = (int*)((char*)d_ws + (size_t)n_nodes * F * sizeof(float));

  build_row_ptr<<<(n_edges + 256) / 256, 256, 0, stream>>>(erow, n_edges,
                                                           n_nodes, row_ptr);
  gemm_xw<<<(n_nodes + 63) / 64, 512, 0, stream>>>(X, W, H, n_nodes);
  spmm_bias_sigmoid<<<(n_nodes + 1) / 2, 128, 0, stream>>>(
      row_ptr, ecol, eval, H, bias, out, n_nodes);
}

// Round 4
// 231.875 us; speedup vs baseline: 1.6956x; 1.2850x over previous
//
#include <hip/hip_runtime.h>
#include <cstddef>

#define F 128    // F_IN == UNITS == 128
#define LDB 136  // LDS row stride in bf16 units: 128 + 8 pad (2-way conflicts only)

typedef __attribute__((ext_vector_type(8))) short bf16x8;
typedef __attribute__((ext_vector_type(4))) float f32x4;

__device__ __forceinline__ unsigned short f2bf(float f) {
  unsigned int u = __float_as_uint(f);
  u += 0x7fffu + ((u >> 16) & 1u);  // round-to-nearest-even
  return (unsigned short)(u >> 16);
}

// ---------------------------------------------------------------------------
// Kernel 0a: row_ptr[N+1] from SORTED erow (edge-parallel, no search).
// Unchanged from round 2 (proven).
// ---------------------------------------------------------------------------
__global__ __launch_bounds__(256) void build_row_ptr(const int* __restrict__ erow,
                                                     int n_edges, int n_nodes,
                                                     int* __restrict__ row_ptr) {
  const int e = blockIdx.x * 256 + threadIdx.x;
  if (e > n_edges) return;
  int r_lo, r_hi, val;
  if (e == 0) {
    r_lo = 0; r_hi = erow[0]; val = 0;
  } else if (e == n_edges) {
    r_lo = erow[n_edges - 1] + 1; r_hi = n_nodes; val = n_edges;
  } else {
    const int rp = erow[e - 1], rc = erow[e];
    r_lo = rp + 1; r_hi = rc; val = e;
  }
  for (int r = r_lo; r <= r_hi; ++r) row_ptr[r] = val;
}

// ---------------------------------------------------------------------------
// Kernel 0b: Wt[n][k] = bf16(W[k][n])  (16K elements, one-shot transpose)
// ---------------------------------------------------------------------------
__global__ __launch_bounds__(256) void convert_w(const float* __restrict__ W,
                                                 unsigned short* __restrict__ Wt) {
  const int idx = blockIdx.x * 256 + threadIdx.x;  // 0..16383
  const int k = idx >> 7, n = idx & 127;
  Wt[n * F + k] = f2bf(W[idx]);
}

// ---------------------------------------------------------------------------
// Kernel 1: H_bf16 = bf16( X @ W )  via MFMA 16x16x32 bf16.
// B (=Wt, k-contiguous) staged once in LDS (34.8 KB). A-fragments are read
// DIRECTLY from global X (8 contiguous floats per lane -> 2x float4) and
// converted to bf16 in registers — no A-LDS, no ushort4 LDS stores.
// 4 waves/block; wave w covers rows w*32..w*32+31 (2 row-tiles x 8 col-tiles).
// Layouts (m89/m120-verified): A/B m|n=lane&15, k=(lane>>4)*8+j;
// C/D col=lane&15, row=(lane>>4)*4+reg.
// ---------------------------------------------------------------------------
__global__ __launch_bounds__(256) void gemm_mfma(const float* __restrict__ X,
                                                 const unsigned short* __restrict__ Wt,
                                                 unsigned short* __restrict__ H,
                                                 int n_nodes) {
  __shared__ alignas(16) unsigned short Bs[128 * LDB];  // 34.8 KB
  const int tid = threadIdx.x;

  // Stage Wt (bf16, k-contiguous): 2048 16B chunks, coalesced
  {
    const uint4* src = (const uint4*)Wt;
    #pragma unroll
    for (int i = 0; i < 8; ++i) {
      const int idx = tid + i * 256;           // 0..2047
      const int n = idx >> 4, c8 = idx & 15;   // 16 chunks per row
      *(uint4*)&Bs[n * LDB + c8 * 8] = src[idx];
    }
  }
  __syncthreads();

  const int wave = tid >> 6;
  const int lane = tid & 63;
  const int l15 = lane & 15;
  const int quad = lane >> 4;
  const int rbase = blockIdx.x * 128 + wave * 32;

  // A-row pointers, clamped (stores are guarded)
  const float* xr[2];
  #pragma unroll
  for (int rt = 0; rt < 2; ++rt) {
    int r = rbase + rt * 16 + l15;
    if (r > n_nodes - 1) r = n_nodes - 1;
    xr[rt] = X + (size_t)r * F;
  }

  f32x4 acc[2][8] = {};

  #pragma unroll
  for (int ks = 0; ks < 4; ++ks) {
    const int k0 = ks * 32 + quad * 8;
    bf16x8 a[2], b[8];
    #pragma unroll
    for (int rt = 0; rt < 2; ++rt) {
      const float4 x0 = *(const float4*)(xr[rt] + k0);
      const float4 x1 = *(const float4*)(xr[rt] + k0 + 4);
      bf16x8 t;
      t[0] = (short)f2bf(x0.x); t[1] = (short)f2bf(x0.y);
      t[2] = (short)f2bf(x0.z); t[3] = (short)f2bf(x0.w);
      t[4] = (short)f2bf(x1.x); t[5] = (short)f2bf(x1.y);
      t[6] = (short)f2bf(x1.z); t[7] = (short)f2bf(x1.w);
      a[rt] = t;
    }
    #pragma unroll
    for (int ct = 0; ct < 8; ++ct)
      b[ct] = *(const bf16x8*)&Bs[(ct * 16 + l15) * LDB + k0];
    #pragma unroll
    for (int rt = 0; rt < 2; ++rt)
      #pragma unroll
      for (int ct = 0; ct < 8; ++ct)
        acc[rt][ct] = __builtin_amdgcn_mfma_f32_16x16x32_bf16(
            a[rt], b[ct], acc[rt][ct], 0, 0, 0);
  }

  // Epilogue: lane (quad,l15) reg r -> row quad*4+r (within 16-tile), col l15
  #pragma unroll
  for (int rt = 0; rt < 2; ++rt) {
    #pragma unroll
    for (int r = 0; r < 4; ++r) {
      const int row = rbase + rt * 16 + quad * 4 + r;
      if (row < n_nodes) {
        #pragma unroll
        for (int ct = 0; ct < 8; ++ct)
          H[(size_t)row * F + ct * 16 + l15] = f2bf(acc[rt][ct][r]);
      }
    }
  }
}

// ---------------------------------------------------------------------------
// Kernel 2: out[n,:] = sigmoid( sum_e val[e]*H[col[e],:] + bias ), H in bf16.
// One wave per node (4 nodes / 256-thread block). Lane covers 2 features via
// one dword load (2x bf16) -> 256B H row per wave per edge, 2 FMA / 4B.
// Edges fetched 64-at-a-time coalesced, broadcast via v_readlane.
// ---------------------------------------------------------------------------
__global__ __launch_bounds__(256) void spmm_bias_sigmoid(
    const int* __restrict__ row_ptr, const int* __restrict__ ecol,
    const float* __restrict__ eval, const unsigned int* __restrict__ H2,
    const float* __restrict__ bias, float* __restrict__ out, int n_nodes) {
  const int wave = threadIdx.x >> 6;
  const int lane = threadIdx.x & 63;
  const int node = blockIdx.x * 4 + wave;
  if (node >= n_nodes) return;

  const int lo = row_ptr[node];
  const int hi = row_ptr[node + 1];
  const int deg = hi - lo;

  float acc0 = 0.f, acc1 = 0.f;
  for (int base = 0; base < deg; base += 64) {
    int cv = 0;
    float vv = 0.f;
    if (base + lane < deg) {
      const int e = lo + base + lane;
      cv = ecol[e];  // coalesced 64-edge batch
      vv = eval[e];
    }
    int cnt = deg - base;
    if (cnt > 64) cnt = 64;
    #pragma unroll 4
    for (int j = 0; j < cnt; ++j) {
      // padded lanes carry c=0, v=0 -> safe H[0,:] load, zero contribution
      const int c = __builtin_amdgcn_readlane(cv, j);
      const float v =
          __int_as_float(__builtin_amdgcn_readlane(__float_as_int(vv), j));
      const unsigned int h = H2[(size_t)c * (F / 2) + lane];  // 2 bf16
      acc0 += v * __uint_as_float(h << 16);
      acc1 += v * __uint_as_float(h & 0xffff0000u);
    }
  }

  const float2 b = *(const float2*)&bias[lane * 2];
  float2 o;
  o.x = 1.f / (1.f + expf(-(acc0 + b.x)));
  o.y = 1.f / (1.f + expf(-(acc1 + b.y)));
  *(float2*)&out[(size_t)node * F + lane * 2] = o;  // 512B/wave coalesced
}

// ---------------------------------------------------------------------------
extern "C" void kernel_launch(void* const* d_in, const int* in_sizes, int n_in,
                              void* d_out, int out_size, void* d_ws, size_t ws_size,
                              hipStream_t stream) {
  const float* X    = (const float*)d_in[0];
  const int*   erow = (const int*)  d_in[1];
  const int*   ecol = (const int*)  d_in[2];
  const float* eval = (const float*)d_in[3];
  const float* W    = (const float*)d_in[4];
  const float* bias = (const float*)d_in[5];
  float* out = (float*)d_out;

  const int n_nodes = in_sizes[0] / F;  // 100000
  const int n_edges = in_sizes[1];      // 1600000

  // Workspace layout (16B aligned):
  //   H  : n_nodes*F bf16   = 25,600,000 B
  //   rp : (n_nodes+1) int  =    400,004 B (padded to 16)
  //   Wt : F*F bf16         =     32,768 B
  char* ws = (char*)d_ws;
  unsigned short* H = (unsigned short*)ws;
  size_t off = (size_t)n_nodes * F * sizeof(unsigned short);
  int* row_ptr = (int*)(ws + off);
  off += ((size_t)(n_nodes + 1) * sizeof(int) + 15) & ~(size_t)15;
  unsigned short* Wt = (unsigned short*)(ws + off);

  convert_w<<<F * F / 256, 256, 0, stream>>>(W, Wt);
  build_row_ptr<<<(n_edges + 256) / 256, 256, 0, stream>>>(erow, n_edges,
                                                           n_nodes, row_ptr);
  gemm_mfma<<<(n_nodes + 127) / 128, 256, 0, stream>>>(X, Wt, H, n_nodes);
  spmm_bias_sigmoid<<<(n_nodes + 3) / 4, 256, 0, stream>>>(
      row_ptr, ecol, eval, (const unsigned int*)H, bias, out, n_nodes);
}

// Round 5
// 196.652 us; speedup vs baseline: 1.9993x; 1.1791x over previous
//
#include <hip/hip_runtime.h>
#include <cstddef>

#define F 128    // F_IN == UNITS == 128
#define LDB 136  // LDS row stride in bf16 units: 128 + 8 pad (2-way conflicts only)

typedef __attribute__((ext_vector_type(8))) short bf16x8;
typedef __attribute__((ext_vector_type(4))) float f32x4;

__device__ __forceinline__ unsigned short f2bf(float f) {
  unsigned int u = __float_as_uint(f);
  u += 0x7fffu + ((u >> 16) & 1u);  // round-to-nearest-even
  return (unsigned short)(u >> 16);
}

// ---------------------------------------------------------------------------
// Kernel 0a: row_ptr[N+1] from SORTED erow (edge-parallel, no search).
// ---------------------------------------------------------------------------
__global__ __launch_bounds__(256) void build_row_ptr(const int* __restrict__ erow,
                                                     int n_edges, int n_nodes,
                                                     int* __restrict__ row_ptr) {
  const int e = blockIdx.x * 256 + threadIdx.x;
  if (e > n_edges) return;
  int r_lo, r_hi, val;
  if (e == 0) {
    r_lo = 0; r_hi = erow[0]; val = 0;
  } else if (e == n_edges) {
    r_lo = erow[n_edges - 1] + 1; r_hi = n_nodes; val = n_edges;
  } else {
    const int rp = erow[e - 1], rc = erow[e];
    r_lo = rp + 1; r_hi = rc; val = e;
  }
  for (int r = r_lo; r <= r_hi; ++r) row_ptr[r] = val;
}

// ---------------------------------------------------------------------------
// Kernel 0b: Wt[n][k] = bf16(W[k][n])
// ---------------------------------------------------------------------------
__global__ __launch_bounds__(256) void convert_w(const float* __restrict__ W,
                                                 unsigned short* __restrict__ Wt) {
  const int idx = blockIdx.x * 256 + threadIdx.x;  // 0..16383
  const int k = idx >> 7, n = idx & 127;
  Wt[n * F + k] = f2bf(W[idx]);
}

// ---------------------------------------------------------------------------
// Kernel 1: H_bf16 = bf16( X @ W )  via MFMA 16x16x32 bf16.
// B (=Wt) staged in LDS; A-fragments straight from global X (reg-convert).
// SWAPPED-OPERAND mfma: D = mfma(b, a) = (X@W)^T in C-layout, i.e. lane
// (quad,l15) holds node row rt*16+l15, features ct*16+quad*4+{0..3} -> each
// (rt,ct) packs to ONE 8B store (16 stores/thread, 32B-contig segments/row)
// instead of round-4's 64 scalar 2B stores (the ~100us epilogue bug).
// ---------------------------------------------------------------------------
__global__ __launch_bounds__(256) void gemm_mfma(const float* __restrict__ X,
                                                 const unsigned short* __restrict__ Wt,
                                                 unsigned short* __restrict__ H,
                                                 int n_nodes) {
  __shared__ alignas(16) unsigned short Bs[128 * LDB];  // 34.8 KB
  const int tid = threadIdx.x;

  {  // stage Wt (bf16, k-contiguous): 2048 16B chunks, coalesced
    const uint4* src = (const uint4*)Wt;
    #pragma unroll
    for (int i = 0; i < 8; ++i) {
      const int idx = tid + i * 256;           // 0..2047
      const int n = idx >> 4, c8 = idx & 15;   // 16 chunks per row
      *(uint4*)&Bs[n * LDB + c8 * 8] = src[idx];
    }
  }
  __syncthreads();

  const int wave = tid >> 6;
  const int lane = tid & 63;
  const int l15 = lane & 15;
  const int quad = lane >> 4;
  const int rbase = blockIdx.x * 128 + wave * 32;

  // A-row pointers, clamped (stores are guarded)
  const float* xr[2];
  #pragma unroll
  for (int rt = 0; rt < 2; ++rt) {
    int r = rbase + rt * 16 + l15;
    if (r > n_nodes - 1) r = n_nodes - 1;
    xr[rt] = X + (size_t)r * F;
  }

  f32x4 acc[2][8] = {};

  #pragma unroll
  for (int ks = 0; ks < 4; ++ks) {
    const int k0 = ks * 32 + quad * 8;
    bf16x8 a[2], b[8];
    #pragma unroll
    for (int rt = 0; rt < 2; ++rt) {
      const float4 x0 = *(const float4*)(xr[rt] + k0);
      const float4 x1 = *(const float4*)(xr[rt] + k0 + 4);
      bf16x8 t;
      t[0] = (short)f2bf(x0.x); t[1] = (short)f2bf(x0.y);
      t[2] = (short)f2bf(x0.z); t[3] = (short)f2bf(x0.w);
      t[4] = (short)f2bf(x1.x); t[5] = (short)f2bf(x1.y);
      t[6] = (short)f2bf(x1.z); t[7] = (short)f2bf(x1.w);
      a[rt] = t;
    }
    #pragma unroll
    for (int ct = 0; ct < 8; ++ct)
      b[ct] = *(const bf16x8*)&Bs[(ct * 16 + l15) * LDB + k0];
    #pragma unroll
    for (int rt = 0; rt < 2; ++rt)
      #pragma unroll
      for (int ct = 0; ct < 8; ++ct)
        acc[rt][ct] = __builtin_amdgcn_mfma_f32_16x16x32_bf16(
            b[ct], a[rt], acc[rt][ct], 0, 0, 0);  // SWAPPED -> transposed D
  }

  // Epilogue: lane holds row rt*16+l15, features ct*16+quad*4+{0..3}
  #pragma unroll
  for (int rt = 0; rt < 2; ++rt) {
    const int row = rbase + rt * 16 + l15;
    if (row < n_nodes) {
      #pragma unroll
      for (int ct = 0; ct < 8; ++ct) {
        const unsigned int d0 = (unsigned int)f2bf(acc[rt][ct][0]) |
                                ((unsigned int)f2bf(acc[rt][ct][1]) << 16);
        const unsigned int d1 = (unsigned int)f2bf(acc[rt][ct][2]) |
                                ((unsigned int)f2bf(acc[rt][ct][3]) << 16);
        uint2 u; u.x = d0; u.y = d1;
        *(uint2*)&H[(size_t)row * F + ct * 16 + quad * 4] = u;  // 8B store
      }
    }
  }
}

// ---------------------------------------------------------------------------
// Kernel 2: out[n,:] = sigmoid( sum_e val[e]*H[col[e],:] + bias ), H bf16.
// 4 nodes per WAVE (16 nodes / 256-thread block). Lane group g (16 lanes)
// owns node g; each lane covers 8 features via ONE dwordx4 (16B) load ->
// one VMEM instr moves 1KB (4 edges x 256B). Edge (col,val) broadcast
// within groups via ds_bpermute. unroll 4 -> 4KB outstanding per wave.
// ---------------------------------------------------------------------------
__global__ __launch_bounds__(256) void spmm_bias_sigmoid(
    const int* __restrict__ row_ptr, const int* __restrict__ ecol,
    const float* __restrict__ eval, const unsigned short* __restrict__ H,
    const float* __restrict__ bias, float* __restrict__ out, int n_nodes) {
  const int wave = threadIdx.x >> 6;
  const int lane = threadIdx.x & 63;
  const int g = lane >> 4;   // group 0..3 = node slot within wave
  const int fl = lane & 15;  // feature-lane: features fl*8 .. fl*8+7
  const int node = blockIdx.x * 16 + wave * 4 + g;
  const bool valid = (node < n_nodes);

  const int lo = valid ? row_ptr[node] : 0;
  const int hi = valid ? row_ptr[node + 1] : 0;
  const int deg = hi - lo;

  // wave-wide max of the 4 group degrees
  int dmax = deg;
  dmax = max(dmax, __shfl_xor(dmax, 16, 64));
  dmax = max(dmax, __shfl_xor(dmax, 32, 64));

  const int bpbase = (lane & 48) * 4;  // byte index of own group's lane 0
  const char* Hb = (const char*)H + fl * 16;

  float acc[8] = {};
  for (int base = 0; base < dmax; base += 16) {
    int voff = 0;
    float vv = 0.f;
    if (base + fl < deg) {
      const int e = lo + base + fl;
      voff = ecol[e] << 8;  // byte offset of H row (c * 256B)
      vv = eval[e];
    }
    int cnt = dmax - base;
    if (cnt > 16) cnt = 16;
    #pragma unroll 4
    for (int j = 0; j < cnt; ++j) {
      const int idx = bpbase + j * 4;
      const int ro = __builtin_amdgcn_ds_bpermute(idx, voff);
      const float v = __int_as_float(
          __builtin_amdgcn_ds_bpermute(idx, __float_as_int(vv)));
      // padded lanes: ro=0, v=0 -> harmless H[0,:] load, zero contribution
      const uint4 h = *(const uint4*)(Hb + ro);
      acc[0] += v * __uint_as_float(h.x << 16);
      acc[1] += v * __uint_as_float(h.x & 0xffff0000u);
      acc[2] += v * __uint_as_float(h.y << 16);
      acc[3] += v * __uint_as_float(h.y & 0xffff0000u);
      acc[4] += v * __uint_as_float(h.z << 16);
      acc[5] += v * __uint_as_float(h.z & 0xffff0000u);
      acc[6] += v * __uint_as_float(h.w << 16);
      acc[7] += v * __uint_as_float(h.w & 0xffff0000u);
    }
  }

  if (valid) {
    const float4 b0 = *(const float4*)&bias[fl * 8];
    const float4 b1 = *(const float4*)&bias[fl * 8 + 4];
    float4 o0, o1;
    o0.x = 1.f / (1.f + expf(-(acc[0] + b0.x)));
    o0.y = 1.f / (1.f + expf(-(acc[1] + b0.y)));
    o0.z = 1.f / (1.f + expf(-(acc[2] + b0.z)));
    o0.w = 1.f / (1.f + expf(-(acc[3] + b0.w)));
    o1.x = 1.f / (1.f + expf(-(acc[4] + b1.x)));
    o1.y = 1.f / (1.f + expf(-(acc[5] + b1.y)));
    o1.z = 1.f / (1.f + expf(-(acc[6] + b1.z)));
    o1.w = 1.f / (1.f + expf(-(acc[7] + b1.w)));
    float* op = out + (size_t)node * F + fl * 8;
    *(float4*)op = o0;          // 16 lanes x 32B = 512B contiguous per node
    *(float4*)(op + 4) = o1;
  }
}

// ---------------------------------------------------------------------------
extern "C" void kernel_launch(void* const* d_in, const int* in_sizes, int n_in,
                              void* d_out, int out_size, void* d_ws, size_t ws_size,
                              hipStream_t stream) {
  const float* X    = (const float*)d_in[0];
  const int*   erow = (const int*)  d_in[1];
  const int*   ecol = (const int*)  d_in[2];
  const float* eval = (const float*)d_in[3];
  const float* W    = (const float*)d_in[4];
  const float* bias = (const float*)d_in[5];
  float* out = (float*)d_out;

  const int n_nodes = in_sizes[0] / F;  // 100000
  const int n_edges = in_sizes[1];      // 1600000

  // Workspace layout (16B aligned):
  //   H  : n_nodes*F bf16   = 25,600,000 B
  //   rp : (n_nodes+1) int  =    400,004 B (padded to 16)
  //   Wt : F*F bf16         =     32,768 B
  char* ws = (char*)d_ws;
  unsigned short* H = (unsigned short*)ws;
  size_t off = (size_t)n_nodes * F * sizeof(unsigned short);
  int* row_ptr = (int*)(ws + off);
  off += ((size_t)(n_nodes + 1) * sizeof(int) + 15) & ~(size_t)15;
  unsigned short* Wt = (unsigned short*)(ws + off);

  convert_w<<<F * F / 256, 256, 0, stream>>>(W, Wt);
  build_row_ptr<<<(n_edges + 256) / 256, 256, 0, stream>>>(erow, n_edges,
                                                           n_nodes, row_ptr);
  gemm_mfma<<<(n_nodes + 127) / 128, 256, 0, stream>>>(X, Wt, H, n_nodes);
  spmm_bias_sigmoid<<<(n_nodes + 15) / 16, 256, 0, stream>>>(
      row_ptr, ecol, eval, H, bias, out, n_nodes);
}

// Round 6
// 192.220 us; speedup vs baseline: 2.0454x; 1.0231x over previous
//
#include <hip/hip_runtime.h>
#include <cstddef>

#define F 128    // F_IN == UNITS == 128
#define LDB 136  // LDS row stride in bf16 units: 128 + 8 pad

typedef __attribute__((ext_vector_type(8))) short bf16x8;
typedef __attribute__((ext_vector_type(4))) float f32x4;

__device__ __forceinline__ unsigned short f2bf(float f) {
  unsigned int u = __float_as_uint(f);
  u += 0x7fffu + ((u >> 16) & 1u);  // round-to-nearest-even
  return (unsigned short)(u >> 16);
}

// ---------------------------------------------------------------------------
// Kernel 0: merged setup. Blocks [0, nbA) build row_ptr[N+1] from SORTED
// erow (edge-parallel); blocks [nbA, nbA+64) transpose+convert W -> Wt bf16.
// ---------------------------------------------------------------------------
__global__ __launch_bounds__(256) void setup(const int* __restrict__ erow,
                                             int n_edges, int n_nodes, int nbA,
                                             int* __restrict__ row_ptr,
                                             const float* __restrict__ W,
                                             unsigned short* __restrict__ Wt) {
  const int bid = blockIdx.x;
  if (bid < nbA) {
    const int e = bid * 256 + threadIdx.x;
    if (e > n_edges) return;
    int r_lo, r_hi, val;
    if (e == 0) {
      r_lo = 0; r_hi = erow[0]; val = 0;
    } else if (e == n_edges) {
      r_lo = erow[n_edges - 1] + 1; r_hi = n_nodes; val = n_edges;
    } else {
      const int rp = erow[e - 1], rc = erow[e];
      r_lo = rp + 1; r_hi = rc; val = e;
    }
    for (int r = r_lo; r <= r_hi; ++r) row_ptr[r] = val;
  } else {
    const int idx = (bid - nbA) * 256 + threadIdx.x;  // 0..16383
    const int k = idx >> 7, n = idx & 127;
    Wt[n * F + k] = f2bf(W[idx]);
  }
}

// ---------------------------------------------------------------------------
// Kernel 1: H_bf16 = bf16( X @ W )  via MFMA 16x16x32 bf16 (unchanged r5).
// Swapped-operand mfma -> D transposed: lane (quad,l15) holds node row
// rt*16+l15, features ct*16+quad*4+{0..3} -> one 8B store per (rt,ct).
// ---------------------------------------------------------------------------
__global__ __launch_bounds__(256) void gemm_mfma(const float* __restrict__ X,
                                                 const unsigned short* __restrict__ Wt,
                                                 unsigned short* __restrict__ H,
                                                 int n_nodes) {
  __shared__ alignas(16) unsigned short Bs[128 * LDB];  // 34.8 KB
  const int tid = threadIdx.x;

  {  // stage Wt (bf16, k-contiguous): 2048 16B chunks, coalesced
    const uint4* src = (const uint4*)Wt;
    #pragma unroll
    for (int i = 0; i < 8; ++i) {
      const int idx = tid + i * 256;
      const int n = idx >> 4, c8 = idx & 15;
      *(uint4*)&Bs[n * LDB + c8 * 8] = src[idx];
    }
  }
  __syncthreads();

  const int wave = tid >> 6;
  const int lane = tid & 63;
  const int l15 = lane & 15;
  const int quad = lane >> 4;
  const int rbase = blockIdx.x * 128 + wave * 32;

  const float* xr[2];
  #pragma unroll
  for (int rt = 0; rt < 2; ++rt) {
    int r = rbase + rt * 16 + l15;
    if (r > n_nodes - 1) r = n_nodes - 1;
    xr[rt] = X + (size_t)r * F;
  }

  f32x4 acc[2][8] = {};

  #pragma unroll
  for (int ks = 0; ks < 4; ++ks) {
    const int k0 = ks * 32 + quad * 8;
    bf16x8 a[2], b[8];
    #pragma unroll
    for (int rt = 0; rt < 2; ++rt) {
      const float4 x0 = *(const float4*)(xr[rt] + k0);
      const float4 x1 = *(const float4*)(xr[rt] + k0 + 4);
      bf16x8 t;
      t[0] = (short)f2bf(x0.x); t[1] = (short)f2bf(x0.y);
      t[2] = (short)f2bf(x0.z); t[3] = (short)f2bf(x0.w);
      t[4] = (short)f2bf(x1.x); t[5] = (short)f2bf(x1.y);
      t[6] = (short)f2bf(x1.z); t[7] = (short)f2bf(x1.w);
      a[rt] = t;
    }
    #pragma unroll
    for (int ct = 0; ct < 8; ++ct)
      b[ct] = *(const bf16x8*)&Bs[(ct * 16 + l15) * LDB + k0];
    #pragma unroll
    for (int rt = 0; rt < 2; ++rt)
      #pragma unroll
      for (int ct = 0; ct < 8; ++ct)
        acc[rt][ct] = __builtin_amdgcn_mfma_f32_16x16x32_bf16(
            b[ct], a[rt], acc[rt][ct], 0, 0, 0);  // swapped -> transposed D
  }

  #pragma unroll
  for (int rt = 0; rt < 2; ++rt) {
    const int row = rbase + rt * 16 + l15;
    if (row < n_nodes) {
      #pragma unroll
      for (int ct = 0; ct < 8; ++ct) {
        const unsigned int d0 = (unsigned int)f2bf(acc[rt][ct][0]) |
                                ((unsigned int)f2bf(acc[rt][ct][1]) << 16);
        const unsigned int d1 = (unsigned int)f2bf(acc[rt][ct][2]) |
                                ((unsigned int)f2bf(acc[rt][ct][3]) << 16);
        uint2 u; u.x = d0; u.y = d1;
        *(uint2*)&H[(size_t)row * F + ct * 16 + quad * 4] = u;
      }
    }
  }
}

// ---------------------------------------------------------------------------
// Kernel 2: out[n,:] = sigmoid( sum_e val[e]*H[col[e],:] + bias ), H bf16.
// 4 nodes per wave; lane group g (16 lanes) owns node g; lane covers 8
// features via one dwordx4. cnt==16 path is FULLY unrolled -> 16 gathers
// (4KB) in flight per wave (round-5 had 4). Remainder path dynamic.
// ---------------------------------------------------------------------------
__global__ __launch_bounds__(256) void spmm_bias_sigmoid(
    const int* __restrict__ row_ptr, const int* __restrict__ ecol,
    const float* __restrict__ eval, const unsigned short* __restrict__ H,
    const float* __restrict__ bias, float* __restrict__ out, int n_nodes) {
  const int wave = threadIdx.x >> 6;
  const int lane = threadIdx.x & 63;
  const int g = lane >> 4;   // node slot within wave
  const int fl = lane & 15;  // feature-lane: features fl*8 .. fl*8+7
  const int node = blockIdx.x * 16 + wave * 4 + g;
  const bool valid = (node < n_nodes);

  const int lo = valid ? row_ptr[node] : 0;
  const int hi = valid ? row_ptr[node + 1] : 0;
  const int deg = hi - lo;

  int dmax = deg;
  dmax = max(dmax, __shfl_xor(dmax, 16, 64));
  dmax = max(dmax, __shfl_xor(dmax, 32, 64));

  const int bpbase = (lane & 48) * 4;  // byte idx of own group's lane 0
  const char* Hb = (const char*)H + fl * 16;

  float acc[8] = {};

#define SPMM_STEP(j)                                                        \
  {                                                                         \
    const int idx = bpbase + (j) * 4;                                       \
    const int ro = __builtin_amdgcn_ds_bpermute(idx, voff);                 \
    const float v = __int_as_float(                                         \
        __builtin_amdgcn_ds_bpermute(idx, __float_as_int(vv)));             \
    const uint4 h = *(const uint4*)(Hb + ro);                               \
    acc[0] += v * __uint_as_float(h.x << 16);                               \
    acc[1] += v * __uint_as_float(h.x & 0xffff0000u);                       \
    acc[2] += v * __uint_as_float(h.y << 16);                               \
    acc[3] += v * __uint_as_float(h.y & 0xffff0000u);                       \
    acc[4] += v * __uint_as_float(h.z << 16);                               \
    acc[5] += v * __uint_as_float(h.z & 0xffff0000u);                       \
    acc[6] += v * __uint_as_float(h.w << 16);                               \
    acc[7] += v * __uint_as_float(h.w & 0xffff0000u);                       \
  }

  for (int base = 0; base < dmax; base += 16) {
    int voff = 0;
    float vv = 0.f;
    if (base + fl < deg) {
      const int e = lo + base + fl;
      voff = ecol[e] << 8;  // byte offset of H row (c * 256B)
      vv = eval[e];
    }
    const int cnt = min(dmax - base, 16);
    if (cnt == 16) {
      #pragma unroll
      for (int j = 0; j < 16; ++j) SPMM_STEP(j)
    } else {
      #pragma unroll 4
      for (int j = 0; j < cnt; ++j) SPMM_STEP(j)
    }
  }
#undef SPMM_STEP

  if (valid) {
    const float4 b0 = *(const float4*)&bias[fl * 8];
    const float4 b1 = *(const float4*)&bias[fl * 8 + 4];
    float4 o0, o1;
    o0.x = 1.f / (1.f + expf(-(acc[0] + b0.x)));
    o0.y = 1.f / (1.f + expf(-(acc[1] + b0.y)));
    o0.z = 1.f / (1.f + expf(-(acc[2] + b0.z)));
    o0.w = 1.f / (1.f + expf(-(acc[3] + b0.w)));
    o1.x = 1.f / (1.f + expf(-(acc[4] + b1.x)));
    o1.y = 1.f / (1.f + expf(-(acc[5] + b1.y)));
    o1.z = 1.f / (1.f + expf(-(acc[6] + b1.z)));
    o1.w = 1.f / (1.f + expf(-(acc[7] + b1.w)));
    float* op = out + (size_t)node * F + fl * 8;
    *(float4*)op = o0;
    *(float4*)(op + 4) = o1;
  }
}

// ---------------------------------------------------------------------------
extern "C" void kernel_launch(void* const* d_in, const int* in_sizes, int n_in,
                              void* d_out, int out_size, void* d_ws, size_t ws_size,
                              hipStream_t stream) {
  const float* X    = (const float*)d_in[0];
  const int*   erow = (const int*)  d_in[1];
  const int*   ecol = (const int*)  d_in[2];
  const float* eval = (const float*)d_in[3];
  const float* W    = (const float*)d_in[4];
  const float* bias = (const float*)d_in[5];
  float* out = (float*)d_out;

  const int n_nodes = in_sizes[0] / F;  // 100000
  const int n_edges = in_sizes[1];      // 1600000

  // Workspace layout (16B aligned):
  //   H  : n_nodes*F bf16   = 25,600,000 B
  //   rp : (n_nodes+1) int  =    400,004 B (padded to 16)
  //   Wt : F*F bf16         =     32,768 B
  char* ws = (char*)d_ws;
  unsigned short* H = (unsigned short*)ws;
  size_t off = (size_t)n_nodes * F * sizeof(unsigned short);
  int* row_ptr = (int*)(ws + off);
  off += ((size_t)(n_nodes + 1) * sizeof(int) + 15) & ~(size_t)15;
  unsigned short* Wt = (unsigned short*)(ws + off);

  const int nbA = (n_edges + 256) / 256;
  const int nbB = (F * F) / 256;  // 64
  setup<<<nbA + nbB, 256, 0, stream>>>(erow, n_edges, n_nodes, nbA, row_ptr,
                                       W, Wt);
  gemm_mfma<<<(n_nodes + 127) / 128, 256, 0, stream>>>(X, Wt, H, n_nodes);
  spmm_bias_sigmoid<<<(n_nodes + 15) / 16, 256, 0, stream>>>(
      row_ptr, ecol, eval, H, bias, out, n_nodes);
}